// Round 16
// baseline (170.920 us; speedup 1.0000x reference)
//
#include <hip/hip_runtime.h>
#include <hip/hip_bf16.h>
#include <hip/hip_fp16.h>

#define T_ 1024
#define S_ 1024
#define B_ 2
#define H_ 16
#define D_ 64
#define E_ 1024
#define M_ (T_*B_)
#define SCALE_ 0.125f
#define LOG2E_ 1.4426950408889634f

typedef __attribute__((ext_vector_type(8))) short short8;
typedef __attribute__((ext_vector_type(8))) _Float16 half8;
typedef __attribute__((ext_vector_type(4))) float f32x4;

#define EXP2 __builtin_amdgcn_exp2f

__device__ __forceinline__ ushort f2bf(float x) {
  unsigned u = __float_as_uint(x);
  unsigned r = (u + 0x7fffu + ((u >> 16) & 1u)) >> 16;
  return (ushort)r;
}
__device__ __forceinline__ float bf2f(ushort h) {
  return __uint_as_float(((unsigned)h) << 16);
}
__device__ __forceinline__ ushort f2h(float x) {
  __half h = __float2half(x);
  return *(ushort*)&h;
}
__device__ __forceinline__ void gld16(const void* g, void* l) {
  __builtin_amdgcn_global_load_lds(
      (const __attribute__((address_space(1))) void*)g,
      (__attribute__((address_space(3))) void*)l, 16, 0, 0);
}
// pack 2 f32 -> 2 bf16 in one u32 (lo = a, hi = b), RNE
__device__ __forceinline__ unsigned cvtpk_bf16(float a, float b) {
  unsigned u;
  asm("v_cvt_pk_bf16_f32 %0, %1, %2" : "=v"(u) : "v"(a), "v"(b));
  return u;
}

// swizzled ushort index within a [*][64] tile (gld16-compatible: key = r&7)
#define SWZ(r, col) ((r)*64 + ((col) ^ (((r)&7)<<3)))

// ---------------------------------------------------------------------------
// fp32 -> bf16 and/or fp16 conversion, multi-tensor
// ---------------------------------------------------------------------------
struct CvtDesc { const float* src; ushort* bf; ushort* h16; int n4; };
struct CvtArgs { CvtDesc d[10]; };

__global__ __launch_bounds__(256) void cvt_kernel(CvtArgs a) {
  const CvtDesc d = a.d[blockIdx.y];
  const int stride = gridDim.x * 256;
  for (int i = blockIdx.x*256 + threadIdx.x; i < d.n4; i += stride) {
    float4 v = ((const float4*)d.src)[i];
    float vals[4] = {v.x, v.y, v.z, v.w};
    if (d.bf) {
      ushort h[4];
      #pragma unroll
      for (int j = 0; j < 4; ++j) h[j] = f2bf(vals[j]);
      ((ushort4*)d.bf)[i] = make_ushort4(h[0],h[1],h[2],h[3]);
    }
    if (d.h16) {
      ushort h[4];
      #pragma unroll
      for (int j = 0; j < 4; ++j) h[j] = f2h(vals[j]);
      ((ushort4*)d.h16)[i] = make_ushort4(h[0],h[1],h[2],h[3]);
    }
  }
}

// ---------------------------------------------------------------------------
// MFMA GEMM: MT(M) x 64(N) tile, BK=64, 4 waves (2Mx2N), SINGLE-buffer LDS,
// XOR-swizzled via pre-swizzled gld16 source col. 1-D grid, XCD remap.
// flags: 1 = tanh, 2 = fp16 in/out          (round-15-proven body)
// ---------------------------------------------------------------------------
struct SegP { const ushort* A; const ushort* W; const float* bias;
              ushort* outb; float* outf; float scale; int flags; };
struct GemmArgs { SegP s[6]; };

template<int MT>
__global__ __launch_bounds__(256) void gemm_mfma(GemmArgs args) {
  constexpr int AG = MT/32;
  constexpr int MI = MT/32;
  constexpr int NY = 2048/MT;
  __shared__ ushort sA[MT*64];
  __shared__ ushort sW[64*64];
  const int id = blockIdx.x;
  const int xcd = id & 7, loc = id >> 3;
  const int x = xcd * ((gridDim.x >> 3) / NY) + loc / NY;
  const int y = loc % NY;
  const SegP sg = args.s[x >> 4];
  const int n0 = (x & 15) * 64;
  const int m0 = y * MT;
  const int tid = threadIdx.x, wv = tid >> 6, lane = tid & 63;
  const int c = lane & 15, g = lane >> 4;
  const int wr = wv >> 1, wc = wv & 1;
  const int lrow = lane >> 3;
  const int scol = ((lane & 7) ^ lrow) * 8;

  size_t aoff[AG], woff[2];
  #pragma unroll
  for (int j = 0; j < AG; ++j) {
    int rg = wv + j*4;
    aoff[j] = (size_t)(m0 + rg*8 + lrow)*1024 + scol;
  }
  #pragma unroll
  for (int j = 0; j < 2; ++j) {
    int rg = wv + j*4;
    woff[j] = (size_t)(n0 + rg*8 + lrow)*1024 + scol;
  }

  const bool isfp16 = (sg.flags & 2) != 0;
  f32x4 acc[MI][2] = {};
  for (int t = 0; t < 16; ++t) {
    const int k0 = t*64;
    #pragma unroll
    for (int j = 0; j < AG; ++j) {
      int rg = wv + j*4;
      gld16(sg.A + aoff[j] + k0, &sA[rg*512]);
    }
    #pragma unroll
    for (int j = 0; j < 2; ++j) {
      int rg = wv + j*4;
      gld16(sg.W + woff[j] + k0, &sW[rg*512]);
    }
    __syncthreads();
    #pragma unroll
    for (int ks = 0; ks < 2; ++ks) {
      short8 af[MI], wf[2];
      #pragma unroll
      for (int mi = 0; mi < MI; ++mi)
        af[mi] = *(const short8*)&sA[SWZ(wr*(MT/2) + mi*16 + c, ks*32 + g*8)];
      #pragma unroll
      for (int ni = 0; ni < 2; ++ni)
        wf[ni] = *(const short8*)&sW[SWZ(wc*32 + ni*16 + c, ks*32 + g*8)];
      if (isfp16) {
        #pragma unroll
        for (int mi = 0; mi < MI; ++mi)
          #pragma unroll
          for (int ni = 0; ni < 2; ++ni)
            acc[mi][ni] = __builtin_amdgcn_mfma_f32_16x16x32_f16(
                *(half8*)&af[mi], *(half8*)&wf[ni], acc[mi][ni], 0, 0, 0);
      } else {
        #pragma unroll
        for (int mi = 0; mi < MI; ++mi)
          #pragma unroll
          for (int ni = 0; ni < 2; ++ni)
            acc[mi][ni] = __builtin_amdgcn_mfma_f32_16x16x32_bf16(
                af[mi], wf[ni], acc[mi][ni], 0, 0, 0);
      }
    }
    __syncthreads();
  }

  #pragma unroll
  for (int ni = 0; ni < 2; ++ni) {
    int col = n0 + wc*32 + ni*16 + c;
    float bias = sg.bias[col];
    #pragma unroll
    for (int mi = 0; mi < MI; ++mi) {
      #pragma unroll
      for (int r = 0; r < 4; ++r) {
        int row = m0 + wr*(MT/2) + mi*16 + 4*g + r;
        float val = (acc[mi][ni][r] + bias) * sg.scale;
        if (sg.flags & 1) val = tanhf(val);
        if (isfp16)       sg.outb[(size_t)row*1024 + col] = f2h(val);
        else if (sg.outf) sg.outf[(size_t)row*1024 + col] = val;
        else              sg.outb[(size_t)row*1024 + col] = f2bf(val);
      }
    }
  }
}

// ---------------------------------------------------------------------------
// V transpose: v_out [token=s*2+b][h*64+d] -> vt [(b*16+h)*64+d][s]
// one block per (bh, 64-s tile); 64x64 tile via LDS
// ---------------------------------------------------------------------------
__global__ __launch_bounds__(256) void vtrans_kernel(
    const ushort* __restrict__ v, ushort* __restrict__ vt) {
  __shared__ ushort tile[64][72];
  const int bh = blockIdx.y;
  const int b = bh >> 4, h = bh & 15;
  const int s0 = blockIdx.x * 64;
  const int tid = threadIdx.x;
  {
    int r = tid >> 2;
    int cch = (tid & 3) * 16;
    size_t src = ((size_t)(s0 + r) * B_ + b) * E_ + h*64 + cch;
    *(uint4*)&tile[r][cch]     = *(const uint4*)&v[src];
    *(uint4*)&tile[r][cch + 8] = *(const uint4*)&v[src + 8];
  }
  __syncthreads();
  {
    int sl = (tid & 15) * 4;
    #pragma unroll
    for (int dp = 0; dp < 4; ++dp) {
      int d = (tid >> 4) + dp * 16;
      ushort4 o = make_ushort4(tile[sl+0][d], tile[sl+1][d],
                               tile[sl+2][d], tile[sl+3][d]);
      *(ushort4*)&vt[((size_t)(bh*64 + d) << 10) + s0 + sl] = o;
    }
  }
}

// ---------------------------------------------------------------------------
// sigma[m] = 1 + sigmoid(sum_e wp_bf[m][e]*Wvp[e] + bvp), one wave per row
// ---------------------------------------------------------------------------
__global__ __launch_bounds__(64) void vp_sigma(const ushort* __restrict__ wp,
    const float* __restrict__ Wvp, const float* __restrict__ bvp,
    float* __restrict__ sigma) {
  const int m = blockIdx.x;
  const int lane = threadIdx.x;
  float acc = 0.f;
  #pragma unroll
  for (int it = 0; it < 2; ++it) {
    int e = lane*8 + it*512;
    short8 a = *(const short8*)&wp[(size_t)m*E_ + e];
    float4 w0 = *(const float4*)&Wvp[e];
    float4 w1 = *(const float4*)&Wvp[e+4];
    acc += bf2f((ushort)a[0])*w0.x + bf2f((ushort)a[1])*w0.y
         + bf2f((ushort)a[2])*w0.z + bf2f((ushort)a[3])*w0.w
         + bf2f((ushort)a[4])*w1.x + bf2f((ushort)a[5])*w1.y
         + bf2f((ushort)a[6])*w1.z + bf2f((ushort)a[7])*w1.w;
  }
  #pragma unroll
  for (int o = 32; o; o >>= 1) acc += __shfl_xor(acc, o);
  if (lane == 0) {
    float gg = acc + bvp[0];
    sigma[m] = 1.f + 1.f/(1.f + __expf(-gg));
  }
}

// ---------------------------------------------------------------------------
// Barrier-free MFMA flash attention with Gaussian bias.
// 1 wave per block, 16 q-rows; K/HK A-fragments and V^T B-fragments read
// DIRECTLY from global (L2-resident; contiguous 16B per lane — identical
// values to the former LDS tiles). Only LDS: 2KB per-wave P redistribution
// (same-wave write->read, no barrier). No __syncthreads anywhere.
// exp2-domain softmax, no online max (bounded logits).
// ---------------------------------------------------------------------------
__global__ __launch_bounds__(64) void attn_mfma(
    const ushort* __restrict__ q_bf, const ushort* __restrict__ k_bf,
    const ushort* __restrict__ vt_bf,
    const ushort* __restrict__ hq_h16, const ushort* __restrict__ hk_h16,
    const float* __restrict__ sigma, ushort* __restrict__ ctx) {
  __shared__ ushort sP[16*64];          // this wave's P tile (2 KB)

  // XCD remap: 2048 blocks, 4 bh per XCD, 64 wave-units (16 q each) per bh
  const int id = blockIdx.x;
  const int loc = id >> 3;
  const int bh = (id & 7) * 4 + (loc >> 6);
  const int b = bh >> 4, h = bh & 15;
  const int qbase = (loc & 63) * 16;
  const int lane = threadIdx.x;
  const int c = lane & 15, g = lane >> 4;

  const size_t qoff = ((size_t)(qbase + c) * B_ + b) * E_ + h * 64;
  short8 qf[2];
  half8  hqf[2];
  #pragma unroll
  for (int cs = 0; cs < 2; ++cs) {
    qf[cs]  = *(const short8*)&q_bf[qoff + cs*32 + g*8];
    hqf[cs] = *(const half8*)&hq_h16[qoff + cs*32 + g*8];
  }

  // K/HK A-fragment base: s = c (+16*m +64*t); elem = cs*32 + g*8 + j
  const size_t kbase = ((size_t)c * B_ + b) * E_ + h*64 + g*8;
  const size_t mstr = (size_t)16 * B_ * E_;
  const size_t tstr = (size_t)64 * B_ * E_;

  // ------------------- pass 1: alignment softmax -> mean -------------------
  float den = 0.f, num = 0.f;
  for (int t = 0; t < 16; ++t) {
    f32x4 acc[4] = {};
    __builtin_amdgcn_s_setprio(1);
    #pragma unroll
    for (int m = 0; m < 4; ++m)
      #pragma unroll
      for (int cs = 0; cs < 2; ++cs)
        acc[m] = __builtin_amdgcn_mfma_f32_16x16x32_f16(
            *(const half8*)&hk_h16[kbase + (size_t)t*tstr + (size_t)m*mstr + cs*32],
            hqf[cs], acc[m], 0, 0, 0);
    __builtin_amdgcn_s_setprio(0);
    float fs = (float)(t*64 + 4*g);
    #pragma unroll
    for (int m = 0; m < 4; ++m)
      #pragma unroll
      for (int r = 0; r < 4; ++r) {
        float e = EXP2(acc[m][r]);
        den += e;
        num += e * (fs + (float)(16*m + r));
      }
  }
  den += __shfl_xor(den, 16); den += __shfl_xor(den, 32);
  num += __shfl_xor(num, 16); num += __shfl_xor(num, 32);
  const float meanq = num / den;             // q = qbase + c
  const float sg = sigma[(size_t)(qbase + c) * B_ + b];
  const float fct = -LOG2E_ / (2.f * sg * sg);

  // ------------------- pass 2: content softmax + PV -------------------------
  f32x4 accO[4] = {};                        // O[q=4g+r][d=16n+c]
  float denq = 0.f;
  const size_t vbase = ((size_t)(bh*64 + c) << 10) + g*8;  // d = c (+16n)
  for (int t = 0; t < 16; ++t) {
    f32x4 accL[4] = {};
    __builtin_amdgcn_s_setprio(1);
    #pragma unroll
    for (int m = 0; m < 4; ++m)
      #pragma unroll
      for (int cs = 0; cs < 2; ++cs)
        accL[m] = __builtin_amdgcn_mfma_f32_16x16x32_bf16(
            *(const short8*)&k_bf[kbase + (size_t)t*tstr + (size_t)m*mstr + cs*32],
            qf[cs], accL[m], 0, 0, 0);
    __builtin_amdgcn_s_setprio(0);

    float fs = (float)(t*64 + 4*g);
    float psum = 0.f;
    #pragma unroll
    for (int m = 0; m < 4; ++m) {
      float pr[4];
      #pragma unroll
      for (int r = 0; r < 4; ++r) {
        float dd = fs + (float)(16*m + r) - meanq;
        pr[r] = EXP2(accL[m][r] + fct * dd * dd);
        psum += pr[r];
      }
      uint2 uu;
      uu.x = cvtpk_bf16(pr[0], pr[1]);
      uu.y = cvtpk_bf16(pr[2], pr[3]);
      *(uint2*)&sP[SWZ(c, 16*m + 4*g)] = uu;
    }
    denq += psum;

    short8 pf[2];
    #pragma unroll
    for (int cs = 0; cs < 2; ++cs)
      pf[cs] = *(const short8*)&sP[SWZ(c, cs*32 + 8*g)];
    __builtin_amdgcn_s_setprio(1);
    #pragma unroll
    for (int n = 0; n < 4; ++n)
      #pragma unroll
      for (int cs = 0; cs < 2; ++cs)
        accO[n] = __builtin_amdgcn_mfma_f32_16x16x32_bf16(
            pf[cs],
            *(const short8*)&vt_bf[vbase + (size_t)(n*16 << 10) + t*64 + cs*32],
            accO[n], 0, 0, 0);
    __builtin_amdgcn_s_setprio(0);
  }

  denq += __shfl_xor(denq, 16);
  denq += __shfl_xor(denq, 32);
  float dinv[4];
  #pragma unroll
  for (int r = 0; r < 4; ++r) dinv[r] = 1.f / __shfl(denq, 4*g + r);

  #pragma unroll
  for (int r = 0; r < 4; ++r) {
    size_t row = ((size_t)(qbase + 4*g + r) * B_ + b) * E_ + h * 64;
    #pragma unroll
    for (int n = 0; n < 4; ++n)
      ctx[row + 16*n + c] = f2bf(accO[n][r] * dinv[r]);
  }
}

// ---------------------------------------------------------------------------
extern "C" void kernel_launch(void* const* d_in, const int* in_sizes, int n_in,
                              void* d_out, int out_size, void* d_ws, size_t ws_size,
                              hipStream_t stream) {
  const float* query  = (const float*)d_in[0];
  const float* key_in = (const float*)d_in[1];
  const float* value  = (const float*)d_in[2];
  const float* Wq  = (const float*)d_in[3];  const float* bq  = (const float*)d_in[4];
  const float* Wk  = (const float*)d_in[5];  const float* bk  = (const float*)d_in[6];
  const float* Wv  = (const float*)d_in[7];  const float* bv  = (const float*)d_in[8];
  const float* Whq = (const float*)d_in[9];  const float* bhq = (const float*)d_in[10];
  const float* Whk = (const float*)d_in[11]; const float* bhk = (const float*)d_in[12];
  const float* Wwp = (const float*)d_in[13]; const float* bwp = (const float*)d_in[14];
  const float* Wvp = (const float*)d_in[15]; const float* bvp = (const float*)d_in[16];
  const float* Wo  = (const float*)d_in[17]; const float* bo  = (const float*)d_in[18];

  const size_t AU = (size_t)M_ * E_;       // 2M elems -> 4MB @16bit
  const size_t WU = (size_t)E_ * E_;       // 1M elems -> 2MB @16bit
  char* p = (char*)d_ws;
  float*  sig       = (float*)p;  p += 16384;
  ushort* query_bf  = (ushort*)p; p += AU*2;
  ushort* key_bf    = (ushort*)p; p += AU*2;
  ushort* value_bf  = (ushort*)p; p += AU*2;
  ushort* query_h16 = (ushort*)p; p += AU*2;   // -> ctx_bf after GEMMs
  ushort* key_h16   = (ushort*)p; p += AU*2;   // -> vt after GEMMs
  ushort* Whq_h16   = (ushort*)p; p += WU*2;
  ushort* Whk_h16   = (ushort*)p; p += WU*2;
  ushort* Wq_bf     = (ushort*)p; p += WU*2;
  ushort* Wk_bf     = (ushort*)p; p += WU*2;
  ushort* Wv_bf     = (ushort*)p; p += WU*2;
  ushort* Wwp_bf    = (ushort*)p; p += WU*2;
  ushort* Wo_bf     = (ushort*)p; p += WU*2;
  ushort* hq_h16    = (ushort*)p; p += AU*2;
  ushort* hk_h16    = (ushort*)p; p += AU*2;
  ushort* q_bf      = (ushort*)p; p += AU*2;
  ushort* k_bf      = (ushort*)p; p += AU*2;
  ushort* v_out     = (ushort*)p; p += AU*2;
  ushort* wp_bf     = (ushort*)p; p += AU*2;   // SEPARATE (round-6 lesson)
  ushort* ctx_bf    = query_h16;               // dead after merged GEMMs
  ushort* vt_bf     = key_h16;                 // dead after merged GEMMs

  // conv: all precision conversions in one launch
  {
    CvtArgs a{};
    a.d[0] = {query,  query_bf, query_h16, (int)(AU/4)};
    a.d[1] = {key_in, key_bf,   key_h16,   (int)(AU/4)};
    a.d[2] = {value,  value_bf, nullptr,   (int)(AU/4)};
    a.d[3] = {Whq,    nullptr,  Whq_h16,   (int)(WU/4)};
    a.d[4] = {Whk,    nullptr,  Whk_h16,   (int)(WU/4)};
    a.d[5] = {Wq,     Wq_bf,    nullptr,   (int)(WU/4)};
    a.d[6] = {Wk,     Wk_bf,    nullptr,   (int)(WU/4)};
    a.d[7] = {Wv,     Wv_bf,    nullptr,   (int)(WU/4)};
    a.d[8] = {Wwp,    Wwp_bf,   nullptr,   (int)(WU/4)};
    a.d[9] = {Wo,     Wo_bf,    nullptr,   (int)(WU/4)};
    cvt_kernel<<<dim3(128, 10), 256, 0, stream>>>(a);
  }
  // ALL 6 projection GEMMs in ONE launch: 64x64 tiles -> 3072 blocks
  {
    GemmArgs a{};
    a.s[0] = {query_bf,  Wq_bf,   bq,  q_bf,   nullptr, SCALE_*LOG2E_, 0};
    a.s[1] = {query_bf,  Wwp_bf,  bwp, wp_bf,  nullptr, 1.f,           1};
    a.s[2] = {key_bf,    Wk_bf,   bk,  k_bf,   nullptr, 1.f,           0};
    a.s[3] = {value_bf,  Wv_bf,   bv,  v_out,  nullptr, 1.f,           0};
    a.s[4] = {query_h16, Whq_h16, bhq, hq_h16, nullptr, SCALE_*LOG2E_, 2};
    a.s[5] = {key_h16,   Whk_h16, bhk, hk_h16, nullptr, 1.f,           2};
    gemm_mfma<64><<<dim3(3072), 256, 0, stream>>>(a);
  }
  // V transpose into vt (key_h16 region, dead after GEMMs)
  vtrans_kernel<<<dim3(16, 32), 256, 0, stream>>>(v_out, vt_bf);
  vp_sigma<<<dim3(M_), dim3(64), 0, stream>>>(wp_bf, Wvp, bvp, sig);
  // barrier-free attention: 2048 one-wave blocks
  attn_mfma<<<dim3(2048), 64, 0, stream>>>(
      q_bf, k_bf, vt_bf, hq_h16, hk_h16, sig, ctx_bf);
  // P3: output projection (fp32 out), 64x64 tiles -> 512 blocks
  {
    GemmArgs a{};
    a.s[0] = {ctx_bf, Wo_bf, bo, nullptr, (float*)d_out, 1.f, 0};
    gemm_mfma<64><<<dim3(512), 256, 0, stream>>>(a);
  }
}

// Round 17
// 120.827 us; speedup vs baseline: 1.4146x; 1.4146x over previous
//
#include <hip/hip_runtime.h>
#include <hip/hip_bf16.h>
#include <hip/hip_fp16.h>

#define T_ 1024
#define S_ 1024
#define B_ 2
#define H_ 16
#define D_ 64
#define E_ 1024
#define M_ (T_*B_)
#define SCALE_ 0.125f
#define LOG2E_ 1.4426950408889634f

typedef __attribute__((ext_vector_type(8))) short short8;
typedef __attribute__((ext_vector_type(8))) _Float16 half8;
typedef __attribute__((ext_vector_type(4))) float f32x4;

#define EXP2 __builtin_amdgcn_exp2f

__device__ __forceinline__ ushort f2bf(float x) {
  unsigned u = __float_as_uint(x);
  unsigned r = (u + 0x7fffu + ((u >> 16) & 1u)) >> 16;
  return (ushort)r;
}
__device__ __forceinline__ float bf2f(ushort h) {
  return __uint_as_float(((unsigned)h) << 16);
}
__device__ __forceinline__ ushort f2h(float x) {
  __half h = __float2half(x);
  return *(ushort*)&h;
}
__device__ __forceinline__ void gld16(const void* g, void* l) {
  __builtin_amdgcn_global_load_lds(
      (const __attribute__((address_space(1))) void*)g,
      (__attribute__((address_space(3))) void*)l, 16, 0, 0);
}
// pack 2 f32 -> 2 bf16 in one u32 (lo = a, hi = b), RNE
__device__ __forceinline__ unsigned cvtpk_bf16(float a, float b) {
  unsigned u;
  asm("v_cvt_pk_bf16_f32 %0, %1, %2" : "=v"(u) : "v"(a), "v"(b));
  return u;
}

// swizzled ushort index within a [*][64] tile (gld16-compatible: key = r&7)
#define SWZ(r, col) ((r)*64 + ((col) ^ (((r)&7)<<3)))

// ---------------------------------------------------------------------------
// fp32 -> bf16 and/or fp16 conversion, multi-tensor
// ---------------------------------------------------------------------------
struct CvtDesc { const float* src; ushort* bf; ushort* h16; int n4; };
struct CvtArgs { CvtDesc d[10]; };

__global__ __launch_bounds__(256) void cvt_kernel(CvtArgs a) {
  const CvtDesc d = a.d[blockIdx.y];
  const int stride = gridDim.x * 256;
  for (int i = blockIdx.x*256 + threadIdx.x; i < d.n4; i += stride) {
    float4 v = ((const float4*)d.src)[i];
    float vals[4] = {v.x, v.y, v.z, v.w};
    if (d.bf) {
      ushort h[4];
      #pragma unroll
      for (int j = 0; j < 4; ++j) h[j] = f2bf(vals[j]);
      ((ushort4*)d.bf)[i] = make_ushort4(h[0],h[1],h[2],h[3]);
    }
    if (d.h16) {
      ushort h[4];
      #pragma unroll
      for (int j = 0; j < 4; ++j) h[j] = f2h(vals[j]);
      ((ushort4*)d.h16)[i] = make_ushort4(h[0],h[1],h[2],h[3]);
    }
  }
}

// ---------------------------------------------------------------------------
// MFMA GEMM: MT(M) x 64(N) tile, BK=64, 4 waves (2Mx2N), SINGLE-buffer LDS,
// XOR-swizzled via pre-swizzled gld16 source col. 1-D grid, XCD remap.
// flags: 1 = tanh, 2 = fp16 in/out          (round-15-proven body)
// ---------------------------------------------------------------------------
struct SegP { const ushort* A; const ushort* W; const float* bias;
              ushort* outb; float* outf; float scale; int flags; };
struct GemmArgs { SegP s[6]; };

template<int MT>
__global__ __launch_bounds__(256) void gemm_mfma(GemmArgs args) {
  constexpr int AG = MT/32;
  constexpr int MI = MT/32;
  constexpr int NY = 2048/MT;
  __shared__ ushort sA[MT*64];
  __shared__ ushort sW[64*64];
  const int id = blockIdx.x;
  const int xcd = id & 7, loc = id >> 3;
  const int x = xcd * ((gridDim.x >> 3) / NY) + loc / NY;
  const int y = loc % NY;
  const SegP sg = args.s[x >> 4];
  const int n0 = (x & 15) * 64;
  const int m0 = y * MT;
  const int tid = threadIdx.x, wv = tid >> 6, lane = tid & 63;
  const int c = lane & 15, g = lane >> 4;
  const int wr = wv >> 1, wc = wv & 1;
  const int lrow = lane >> 3;
  const int scol = ((lane & 7) ^ lrow) * 8;

  size_t aoff[AG], woff[2];
  #pragma unroll
  for (int j = 0; j < AG; ++j) {
    int rg = wv + j*4;
    aoff[j] = (size_t)(m0 + rg*8 + lrow)*1024 + scol;
  }
  #pragma unroll
  for (int j = 0; j < 2; ++j) {
    int rg = wv + j*4;
    woff[j] = (size_t)(n0 + rg*8 + lrow)*1024 + scol;
  }

  const bool isfp16 = (sg.flags & 2) != 0;
  f32x4 acc[MI][2] = {};
  for (int t = 0; t < 16; ++t) {
    const int k0 = t*64;
    #pragma unroll
    for (int j = 0; j < AG; ++j) {
      int rg = wv + j*4;
      gld16(sg.A + aoff[j] + k0, &sA[rg*512]);
    }
    #pragma unroll
    for (int j = 0; j < 2; ++j) {
      int rg = wv + j*4;
      gld16(sg.W + woff[j] + k0, &sW[rg*512]);
    }
    __syncthreads();
    #pragma unroll
    for (int ks = 0; ks < 2; ++ks) {
      short8 af[MI], wf[2];
      #pragma unroll
      for (int mi = 0; mi < MI; ++mi)
        af[mi] = *(const short8*)&sA[SWZ(wr*(MT/2) + mi*16 + c, ks*32 + g*8)];
      #pragma unroll
      for (int ni = 0; ni < 2; ++ni)
        wf[ni] = *(const short8*)&sW[SWZ(wc*32 + ni*16 + c, ks*32 + g*8)];
      if (isfp16) {
        #pragma unroll
        for (int mi = 0; mi < MI; ++mi)
          #pragma unroll
          for (int ni = 0; ni < 2; ++ni)
            acc[mi][ni] = __builtin_amdgcn_mfma_f32_16x16x32_f16(
                *(half8*)&af[mi], *(half8*)&wf[ni], acc[mi][ni], 0, 0, 0);
      } else {
        #pragma unroll
        for (int mi = 0; mi < MI; ++mi)
          #pragma unroll
          for (int ni = 0; ni < 2; ++ni)
            acc[mi][ni] = __builtin_amdgcn_mfma_f32_16x16x32_bf16(
                af[mi], wf[ni], acc[mi][ni], 0, 0, 0);
      }
    }
    __syncthreads();
  }

  #pragma unroll
  for (int ni = 0; ni < 2; ++ni) {
    int col = n0 + wc*32 + ni*16 + c;
    float bias = sg.bias[col];
    #pragma unroll
    for (int mi = 0; mi < MI; ++mi) {
      #pragma unroll
      for (int r = 0; r < 4; ++r) {
        int row = m0 + wr*(MT/2) + mi*16 + 4*g + r;
        float val = (acc[mi][ni][r] + bias) * sg.scale;
        if (sg.flags & 1) val = tanhf(val);
        if (isfp16)       sg.outb[(size_t)row*1024 + col] = f2h(val);
        else if (sg.outf) sg.outf[(size_t)row*1024 + col] = val;
        else              sg.outb[(size_t)row*1024 + col] = f2bf(val);
      }
    }
  }
}

// ---------------------------------------------------------------------------
// sigma[m] = 1 + sigmoid(sum_e wp_bf[m][e]*Wvp[e] + bvp), one wave per row
// ---------------------------------------------------------------------------
__global__ __launch_bounds__(64) void vp_sigma(const ushort* __restrict__ wp,
    const float* __restrict__ Wvp, const float* __restrict__ bvp,
    float* __restrict__ sigma) {
  const int m = blockIdx.x;
  const int lane = threadIdx.x;
  float acc = 0.f;
  #pragma unroll
  for (int it = 0; it < 2; ++it) {
    int e = lane*8 + it*512;
    short8 a = *(const short8*)&wp[(size_t)m*E_ + e];
    float4 w0 = *(const float4*)&Wvp[e];
    float4 w1 = *(const float4*)&Wvp[e+4];
    acc += bf2f((ushort)a[0])*w0.x + bf2f((ushort)a[1])*w0.y
         + bf2f((ushort)a[2])*w0.z + bf2f((ushort)a[3])*w0.w
         + bf2f((ushort)a[4])*w1.x + bf2f((ushort)a[5])*w1.y
         + bf2f((ushort)a[6])*w1.z + bf2f((ushort)a[7])*w1.w;
  }
  #pragma unroll
  for (int o = 32; o; o >>= 1) acc += __shfl_xor(acc, o);
  if (lane == 0) {
    float gg = acc + bvp[0];
    sigma[m] = 1.f + 1.f/(1.f + __expf(-gg));
  }
}

// ---------------------------------------------------------------------------
// MFMA flash attention with Gaussian bias, 2-phase double-buffered, no
// online max (bounded logits), exp2-domain. Round-10-proven body with
// 2 WAVES per block (32 q) -> 1024 blocks -> 4 independent barrier groups
// per CU (was 2). Only the wave-count geometry changed: per-wave K staging
// covers 32 rows (4 gld16); V staging remapped for 128 threads (4 s-rows
// per thread). Fragment layouts, swizzles, lane math identical.
// ---------------------------------------------------------------------------
__global__ __launch_bounds__(128) void attn_mfma(
    const ushort* __restrict__ q_bf, const ushort* __restrict__ k_bf,
    const ushort* __restrict__ v_bf,
    const ushort* __restrict__ hq_h16, const ushort* __restrict__ hk_h16,
    const float* __restrict__ sigma, ushort* __restrict__ ctx) {
  __shared__ ushort sK[2][64*64];
  __shared__ ushort sV[2][64*64];
  __shared__ ushort sP[2][16*64];

  // XCD remap: 1024 blocks, 4 bh per XCD, 32 q-tiles (32 q each) per bh
  const int id = blockIdx.x;
  const int loc = id >> 3;
  const int bh = (id & 7) * 4 + (loc >> 5);
  const int b = bh >> 4, h = bh & 15;
  const int t0 = (loc & 31) * 32;
  const int tid = threadIdx.x;
  const int wv = tid >> 6, lane = tid & 63;
  const int c = lane & 15, g = lane >> 4;
  const int qbase = t0 + wv * 16;
  const size_t rowstr = (size_t)B_ * E_;
  const size_t qoff = ((size_t)(qbase + c) * B_ + b) * E_ + h * 64;

  short8 qf[2];
  half8  hqf[2];
  #pragma unroll
  for (int cs = 0; cs < 2; ++cs) {
    qf[cs]  = *(const short8*)&q_bf[qoff + cs*32 + g*8];
    hqf[cs] = *(const half8*)&hq_h16[qoff + cs*32 + g*8];
  }

  // K staging: wave wv stages rows [wv*32, wv*32+32), 4 gld16
  const int lrow = lane >> 3;
  const int chk = ((lane & 7) ^ lrow) * 8;        // row&7 == lrow for all j
  size_t kgoff[4];
  #pragma unroll
  for (int j = 0; j < 4; ++j) {
    int row = wv*32 + j*8 + lrow;
    kgoff[j] = ((size_t)row * B_ + b) * E_ + h*64 + chk;
  }
  #define KSTAGE(dst, src, soff)                                      \
    _Pragma("unroll")                                                 \
    for (int j = 0; j < 4; ++j)                                       \
      gld16((src) + kgoff[j] + (size_t)(soff) * rowstr,               \
            &(dst)[(wv*32 + j*8)*64]);

  // V staging geometry: 128 threads, 4 s-rows x 8 d each
  const int s2v = (tid & 15) * 4;
  const int d0v = (tid >> 4) * 8;

  // ------------------- pass 1: alignment softmax -> mean -------------------
  float den = 0.f, num = 0.f;
  {
    KSTAGE(sK[0], hk_h16, 0);
    __syncthreads();
    for (int t = 0; t < 16; ++t) {
      const ushort* kb = sK[t & 1];
      if (t < 15) { KSTAGE(sK[(t+1) & 1], hk_h16, (t+1)*64); }
      f32x4 acc[4] = {};
      __builtin_amdgcn_s_setprio(1);
      #pragma unroll
      for (int m = 0; m < 4; ++m)
        #pragma unroll
        for (int cs = 0; cs < 2; ++cs)
          acc[m] = __builtin_amdgcn_mfma_f32_16x16x32_f16(
              *(const half8*)&kb[SWZ(c + 16*m, cs*32 + g*8)], hqf[cs], acc[m], 0,0,0);
      __builtin_amdgcn_s_setprio(0);

      float fs = (float)(t*64 + 4*g);
      #pragma unroll
      for (int m = 0; m < 4; ++m)
        #pragma unroll
        for (int r = 0; r < 4; ++r) {
          float e = EXP2(acc[m][r]);
          den += e;
          num += e * (fs + (float)(16*m + r));
        }
      __syncthreads();
    }
  }
  den += __shfl_xor(den, 16); den += __shfl_xor(den, 32);
  num += __shfl_xor(num, 16); num += __shfl_xor(num, 32);
  const float meanq = num / den;              // q = qbase + c (uniform in g)
  const float sg = sigma[(size_t)(qbase + c) * B_ + b];
  const float fct = -LOG2E_ / (2.f * sg * sg);

  // ------------------- pass 2: content softmax + PV -------------------------
  f32x4 accO[4] = {};                         // O[q=4g+r][d=16n+c]
  float denq = 0.f;
  {
    KSTAGE(sK[0], k_bf, 0);
    {
      size_t off0 = ((size_t)s2v * B_ + b) * E_ + h * 64 + d0v;
      uint4 r0 = *(const uint4*)&v_bf[off0];
      uint4 r1 = *(const uint4*)&v_bf[off0 + rowstr];
      uint4 r2 = *(const uint4*)&v_bf[off0 + 2*rowstr];
      uint4 r3 = *(const uint4*)&v_bf[off0 + 3*rowstr];
      const ushort *p0 = (const ushort*)&r0, *p1 = (const ushort*)&r1;
      const ushort *p2 = (const ushort*)&r2, *p3 = (const ushort*)&r3;
      #pragma unroll
      for (int j = 0; j < 8; ++j) {
        *(unsigned*)&sV[0][SWZ(d0v + j, s2v)]     = (unsigned)p0[j] | ((unsigned)p1[j] << 16);
        *(unsigned*)&sV[0][SWZ(d0v + j, s2v + 2)] = (unsigned)p2[j] | ((unsigned)p3[j] << 16);
      }
    }
    __syncthreads();

    for (int t = 0; t < 16; ++t) {
      const int cur = t & 1;
      const ushort* kb = sK[cur];
      const ushort* vb = sV[cur];
      uint4 r0, r1, r2, r3;
      if (t < 15) {
        KSTAGE(sK[cur^1], k_bf, (t+1)*64);
        size_t off0 = ((size_t)((t+1)*64 + s2v) * B_ + b) * E_ + h * 64 + d0v;
        r0 = *(const uint4*)&v_bf[off0];
        r1 = *(const uint4*)&v_bf[off0 + rowstr];
        r2 = *(const uint4*)&v_bf[off0 + 2*rowstr];
        r3 = *(const uint4*)&v_bf[off0 + 3*rowstr];
      }

      f32x4 accL[4] = {};
      __builtin_amdgcn_s_setprio(1);
      #pragma unroll
      for (int m = 0; m < 4; ++m)
        #pragma unroll
        for (int cs = 0; cs < 2; ++cs)
          accL[m] = __builtin_amdgcn_mfma_f32_16x16x32_bf16(
              *(const short8*)&kb[SWZ(c + 16*m, cs*32 + g*8)], qf[cs], accL[m], 0,0,0);
      __builtin_amdgcn_s_setprio(0);

      float fs = (float)(t*64 + 4*g);
      float psum = 0.f;
      #pragma unroll
      for (int m = 0; m < 4; ++m) {
        float pr[4];
        #pragma unroll
        for (int r = 0; r < 4; ++r) {
          float dd = fs + (float)(16*m + r) - meanq;
          pr[r] = EXP2(accL[m][r] + fct * dd * dd);
          psum += pr[r];
        }
        uint2 uu;
        uu.x = cvtpk_bf16(pr[0], pr[1]);
        uu.y = cvtpk_bf16(pr[2], pr[3]);
        *(uint2*)&sP[wv][SWZ(c, 16*m + 4*g)] = uu;
      }
      denq += psum;

      __builtin_amdgcn_s_setprio(1);
      #pragma unroll
      for (int n = 0; n < 4; ++n)
        #pragma unroll
        for (int cs = 0; cs < 2; ++cs)
          accO[n] = __builtin_amdgcn_mfma_f32_16x16x32_bf16(
              *(const short8*)&sP[wv][SWZ(c, cs*32 + 8*g)],
              *(const short8*)&vb[SWZ(c + 16*n, cs*32 + 8*g)],
              accO[n], 0,0,0);
      __builtin_amdgcn_s_setprio(0);

      if (t < 15) {
        const ushort *p0 = (const ushort*)&r0, *p1 = (const ushort*)&r1;
        const ushort *p2 = (const ushort*)&r2, *p3 = (const ushort*)&r3;
        #pragma unroll
        for (int j = 0; j < 8; ++j) {
          *(unsigned*)&sV[cur^1][SWZ(d0v + j, s2v)]     = (unsigned)p0[j] | ((unsigned)p1[j] << 16);
          *(unsigned*)&sV[cur^1][SWZ(d0v + j, s2v + 2)] = (unsigned)p2[j] | ((unsigned)p3[j] << 16);
        }
      }
      __syncthreads();
    }
  }
  #undef KSTAGE

  denq += __shfl_xor(denq, 16);
  denq += __shfl_xor(denq, 32);
  float dinv[4];
  #pragma unroll
  for (int r = 0; r < 4; ++r) dinv[r] = 1.f / __shfl(denq, 4*g + r);

  #pragma unroll
  for (int r = 0; r < 4; ++r) {
    size_t row = ((size_t)(qbase + 4*g + r) * B_ + b) * E_ + h * 64;
    #pragma unroll
    for (int n = 0; n < 4; ++n)
      ctx[row + 16*n + c] = f2bf(accO[n][r] * dinv[r]);
  }
}

// ---------------------------------------------------------------------------
extern "C" void kernel_launch(void* const* d_in, const int* in_sizes, int n_in,
                              void* d_out, int out_size, void* d_ws, size_t ws_size,
                              hipStream_t stream) {
  const float* query  = (const float*)d_in[0];
  const float* key_in = (const float*)d_in[1];
  const float* value  = (const float*)d_in[2];
  const float* Wq  = (const float*)d_in[3];  const float* bq  = (const float*)d_in[4];
  const float* Wk  = (const float*)d_in[5];  const float* bk  = (const float*)d_in[6];
  const float* Wv  = (const float*)d_in[7];  const float* bv  = (const float*)d_in[8];
  const float* Whq = (const float*)d_in[9];  const float* bhq = (const float*)d_in[10];
  const float* Whk = (const float*)d_in[11]; const float* bhk = (const float*)d_in[12];
  const float* Wwp = (const float*)d_in[13]; const float* bwp = (const float*)d_in[14];
  const float* Wvp = (const float*)d_in[15]; const float* bvp = (const float*)d_in[16];
  const float* Wo  = (const float*)d_in[17]; const float* bo  = (const float*)d_in[18];

  const size_t AU = (size_t)M_ * E_;       // 2M elems -> 4MB @16bit
  const size_t WU = (size_t)E_ * E_;       // 1M elems -> 2MB @16bit
  char* p = (char*)d_ws;
  float*  sig       = (float*)p;  p += 16384;
  ushort* query_bf  = (ushort*)p; p += AU*2;
  ushort* key_bf    = (ushort*)p; p += AU*2;
  ushort* value_bf  = (ushort*)p; p += AU*2;
  ushort* query_h16 = (ushort*)p; p += AU*2;   // -> ctx_bf after GEMMs
  ushort* key_h16   = (ushort*)p; p += AU*2;
  ushort* Whq_h16   = (ushort*)p; p += WU*2;
  ushort* Whk_h16   = (ushort*)p; p += WU*2;
  ushort* Wq_bf     = (ushort*)p; p += WU*2;
  ushort* Wk_bf     = (ushort*)p; p += WU*2;
  ushort* Wv_bf     = (ushort*)p; p += WU*2;
  ushort* Wwp_bf    = (ushort*)p; p += WU*2;
  ushort* Wo_bf     = (ushort*)p; p += WU*2;
  ushort* hq_h16    = (ushort*)p; p += AU*2;
  ushort* hk_h16    = (ushort*)p; p += AU*2;
  ushort* q_bf      = (ushort*)p; p += AU*2;
  ushort* k_bf      = (ushort*)p; p += AU*2;
  ushort* v_out     = (ushort*)p; p += AU*2;
  ushort* wp_bf     = (ushort*)p; p += AU*2;   // SEPARATE (round-6 lesson)
  ushort* ctx_bf    = query_h16;               // dead after merged GEMMs

  // conv: all precision conversions in one launch
  {
    CvtArgs a{};
    a.d[0] = {query,  query_bf, query_h16, (int)(AU/4)};
    a.d[1] = {key_in, key_bf,   key_h16,   (int)(AU/4)};
    a.d[2] = {value,  value_bf, nullptr,   (int)(AU/4)};
    a.d[3] = {Whq,    nullptr,  Whq_h16,   (int)(WU/4)};
    a.d[4] = {Whk,    nullptr,  Whk_h16,   (int)(WU/4)};
    a.d[5] = {Wq,     Wq_bf,    nullptr,   (int)(WU/4)};
    a.d[6] = {Wk,     Wk_bf,    nullptr,   (int)(WU/4)};
    a.d[7] = {Wv,     Wv_bf,    nullptr,   (int)(WU/4)};
    a.d[8] = {Wwp,    Wwp_bf,   nullptr,   (int)(WU/4)};
    a.d[9] = {Wo,     Wo_bf,    nullptr,   (int)(WU/4)};
    cvt_kernel<<<dim3(128, 10), 256, 0, stream>>>(a);
  }
  // ALL 6 projection GEMMs in ONE launch: 64x64 tiles -> 3072 blocks
  {
    GemmArgs a{};
    a.s[0] = {query_bf,  Wq_bf,   bq,  q_bf,   nullptr, SCALE_*LOG2E_, 0};
    a.s[1] = {query_bf,  Wwp_bf,  bwp, wp_bf,  nullptr, 1.f,           1};
    a.s[2] = {key_bf,    Wk_bf,   bk,  k_bf,   nullptr, 1.f,           0};
    a.s[3] = {value_bf,  Wv_bf,   bv,  v_out,  nullptr, 1.f,           0};
    a.s[4] = {query_h16, Whq_h16, bhq, hq_h16, nullptr, SCALE_*LOG2E_, 2};
    a.s[5] = {key_h16,   Whk_h16, bhk, hk_h16, nullptr, 1.f,           2};
    gemm_mfma<64><<<dim3(3072), 256, 0, stream>>>(a);
  }
  vp_sigma<<<dim3(M_), dim3(64), 0, stream>>>(wp_bf, Wvp, bvp, sig);
  // attention: 1024 two-wave blocks (4 barrier groups / CU)
  attn_mfma<<<dim3(1024), 128, 0, stream>>>(
      q_bf, k_bf, v_out, hq_h16, hk_h16, sig, ctx_bf);
  // P3: output projection (fp32 out), 64x64 tiles -> 512 blocks
  {
    GemmArgs a{};
    a.s[0] = {ctx_bf, Wo_bf, bo, nullptr, (float*)d_out, 1.f, 0};
    gemm_mfma<64><<<dim3(512), 256, 0, stream>>>(a);
  }
}

// Round 18
// 111.128 us; speedup vs baseline: 1.5380x; 1.0873x over previous
//
#include <hip/hip_runtime.h>
#include <hip/hip_bf16.h>
#include <hip/hip_fp16.h>

#define T_ 1024
#define S_ 1024
#define B_ 2
#define H_ 16
#define D_ 64
#define E_ 1024
#define M_ (T_*B_)
#define SCALE_ 0.125f
#define LOG2E_ 1.4426950408889634f

typedef __attribute__((ext_vector_type(8))) short short8;
typedef __attribute__((ext_vector_type(8))) _Float16 half8;
typedef __attribute__((ext_vector_type(4))) float f32x4;

#define EXP2 __builtin_amdgcn_exp2f

__device__ __forceinline__ ushort f2bf(float x) {
  unsigned u = __float_as_uint(x);
  unsigned r = (u + 0x7fffu + ((u >> 16) & 1u)) >> 16;
  return (ushort)r;
}
__device__ __forceinline__ float bf2f(ushort h) {
  return __uint_as_float(((unsigned)h) << 16);
}
__device__ __forceinline__ ushort f2h(float x) {
  __half h = __float2half(x);
  return *(ushort*)&h;
}
__device__ __forceinline__ void gld16(const void* g, void* l) {
  __builtin_amdgcn_global_load_lds(
      (const __attribute__((address_space(1))) void*)g,
      (__attribute__((address_space(3))) void*)l, 16, 0, 0);
}
// pack 2 f32 -> 2 bf16 in one u32 (lo = a, hi = b), RNE
__device__ __forceinline__ unsigned cvtpk_bf16(float a, float b) {
  unsigned u;
  asm("v_cvt_pk_bf16_f32 %0, %1, %2" : "=v"(u) : "v"(a), "v"(b));
  return u;
}

// swizzled ushort index within a [*][64] tile (gld16-compatible: key = r&7)
#define SWZ(r, col) ((r)*64 + ((col) ^ (((r)&7)<<3)))

// ---------------------------------------------------------------------------
// fp32 -> bf16 and/or fp16 conversion, multi-tensor; also zeroes sig_raw
// ---------------------------------------------------------------------------
struct CvtDesc { const float* src; ushort* bf; ushort* h16; int n4; };
struct CvtArgs { CvtDesc d[10]; float* zero; int zn; };

__global__ __launch_bounds__(256) void cvt_kernel(CvtArgs a) {
  if (a.zero && blockIdx.y == 0) {
    for (int i = blockIdx.x*256 + threadIdx.x; i < a.zn; i += gridDim.x*256)
      a.zero[i] = 0.f;
  }
  const CvtDesc d = a.d[blockIdx.y];
  const int stride = gridDim.x * 256;
  for (int i = blockIdx.x*256 + threadIdx.x; i < d.n4; i += stride) {
    float4 v = ((const float4*)d.src)[i];
    float vals[4] = {v.x, v.y, v.z, v.w};
    if (d.bf) {
      ushort h[4];
      #pragma unroll
      for (int j = 0; j < 4; ++j) h[j] = f2bf(vals[j]);
      ((ushort4*)d.bf)[i] = make_ushort4(h[0],h[1],h[2],h[3]);
    }
    if (d.h16) {
      ushort h[4];
      #pragma unroll
      for (int j = 0; j < 4; ++j) h[j] = f2h(vals[j]);
      ((ushort4*)d.h16)[i] = make_ushort4(h[0],h[1],h[2],h[3]);
    }
  }
}

// ---------------------------------------------------------------------------
// MFMA GEMM: MT(M) x 64(N) tile, BK=64, 4 waves (2Mx2N), SINGLE-buffer LDS
// (round-10-proven structure), XOR-swizzled LDS via pre-swizzled gld16
// source col. 1-D grid, XCD-aware bijective remap (all m-tiles of each
// (seg,n-chunk) grouped per XCD; m-tile fastest).
// flags: 1 = tanh + fused sigma partial (no store; outf = sig_raw, vp = Wvp),
//        2 = fp16 in/out
// ---------------------------------------------------------------------------
struct SegP { const ushort* A; const ushort* W; const float* bias;
              ushort* outb; float* outf; const float* vp; float scale; int flags; };
struct GemmArgs { SegP s[6]; };

template<int MT>
__global__ __launch_bounds__(256) void gemm_mfma(GemmArgs args) {
  constexpr int AG = MT/32;          // A row-groups staged per wave
  constexpr int MI = MT/32;          // fragment rows per wave
  constexpr int NY = 2048/MT;        // m-tiles
  __shared__ ushort sA[MT*64];
  __shared__ ushort sW[64*64];
  // XCD-aware remap: id -> (x = seg*16 + n-tile, y = m-tile), y fastest
  const int id = blockIdx.x;
  const int xcd = id & 7, loc = id >> 3;
  const int x = xcd * ((gridDim.x >> 3) / NY) + loc / NY;
  const int y = loc % NY;
  const SegP sg = args.s[x >> 4];
  const int n0 = (x & 15) * 64;
  const int m0 = y * MT;
  const int tid = threadIdx.x, wv = tid >> 6, lane = tid & 63;
  const int c = lane & 15, g = lane >> 4;
  const int wr = wv >> 1, wc = wv & 1;
  const int lrow = lane >> 3;                       // row within 8-row group
  const int scol = ((lane & 7) ^ lrow) * 8;         // pre-swizzled source col

  size_t aoff[AG], woff[2];
  #pragma unroll
  for (int j = 0; j < AG; ++j) {
    int rg = wv + j*4;
    aoff[j] = (size_t)(m0 + rg*8 + lrow)*1024 + scol;
  }
  #pragma unroll
  for (int j = 0; j < 2; ++j) {
    int rg = wv + j*4;
    woff[j] = (size_t)(n0 + rg*8 + lrow)*1024 + scol;
  }

  const bool isfp16 = (sg.flags & 2) != 0;
  f32x4 acc[MI][2] = {};
  for (int t = 0; t < 16; ++t) {
    const int k0 = t*64;
    #pragma unroll
    for (int j = 0; j < AG; ++j) {
      int rg = wv + j*4;
      gld16(sg.A + aoff[j] + k0, &sA[rg*512]);
    }
    #pragma unroll
    for (int j = 0; j < 2; ++j) {
      int rg = wv + j*4;
      gld16(sg.W + woff[j] + k0, &sW[rg*512]);
    }
    __syncthreads();
    #pragma unroll
    for (int ks = 0; ks < 2; ++ks) {
      short8 af[MI], wf[2];
      #pragma unroll
      for (int mi = 0; mi < MI; ++mi)
        af[mi] = *(const short8*)&sA[SWZ(wr*(MT/2) + mi*16 + c, ks*32 + g*8)];
      #pragma unroll
      for (int ni = 0; ni < 2; ++ni)
        wf[ni] = *(const short8*)&sW[SWZ(wc*32 + ni*16 + c, ks*32 + g*8)];
      if (isfp16) {
        #pragma unroll
        for (int mi = 0; mi < MI; ++mi)
          #pragma unroll
          for (int ni = 0; ni < 2; ++ni)
            acc[mi][ni] = __builtin_amdgcn_mfma_f32_16x16x32_f16(
                *(half8*)&af[mi], *(half8*)&wf[ni], acc[mi][ni], 0, 0, 0);
      } else {
        #pragma unroll
        for (int mi = 0; mi < MI; ++mi)
          #pragma unroll
          for (int ni = 0; ni < 2; ++ni)
            acc[mi][ni] = __builtin_amdgcn_mfma_f32_16x16x32_bf16(
                af[mi], wf[ni], acc[mi][ni], 0, 0, 0);
      }
    }
    __syncthreads();
  }

  if (sg.flags & 1) {
    // wp segment: tanh, then fused sigma partial (g = sum tanh(..)*Wvp),
    // 16-lane shfl reduce per row, one atomicAdd per (row, wave).
    const int col0 = n0 + wc*32 + c, col1 = col0 + 16;
    const float b0 = sg.bias[col0], b1 = sg.bias[col1];
    const float w0 = sg.vp[col0],  w1 = sg.vp[col1];
    #pragma unroll
    for (int mi = 0; mi < MI; ++mi) {
      #pragma unroll
      for (int r = 0; r < 4; ++r) {
        float v0 = tanhf((acc[mi][0][r] + b0) * sg.scale);
        float v1 = tanhf((acc[mi][1][r] + b1) * sg.scale);
        float part = v0*w0 + v1*w1;
        part += __shfl_xor(part, 1);
        part += __shfl_xor(part, 2);
        part += __shfl_xor(part, 4);
        part += __shfl_xor(part, 8);
        if (c == 0) {
          int row = m0 + wr*(MT/2) + mi*16 + 4*g + r;
          atomicAdd(&sg.outf[row], part);
        }
      }
    }
  } else {
    #pragma unroll
    for (int ni = 0; ni < 2; ++ni) {
      int col = n0 + wc*32 + ni*16 + c;
      float bias = sg.bias[col];
      #pragma unroll
      for (int mi = 0; mi < MI; ++mi) {
        #pragma unroll
        for (int r = 0; r < 4; ++r) {
          int row = m0 + wr*(MT/2) + mi*16 + 4*g + r;
          float val = (acc[mi][ni][r] + bias) * sg.scale;
          if (isfp16)       sg.outb[(size_t)row*1024 + col] = f2h(val);
          else if (sg.outf) sg.outf[(size_t)row*1024 + col] = val;
          else              sg.outb[(size_t)row*1024 + col] = f2bf(val);
        }
      }
    }
  }
}

// ---------------------------------------------------------------------------
// MFMA flash attention with Gaussian bias, 2-phase double-buffered, no
// online max (bounded logits), exp2-domain. Round-9/10 body; sigma is
// computed inline from the fused raw accumulator (g + bvp -> sigmoid).
// ---------------------------------------------------------------------------
__global__ __launch_bounds__(256) void attn_mfma(
    const ushort* __restrict__ q_bf, const ushort* __restrict__ k_bf,
    const ushort* __restrict__ v_bf,
    const ushort* __restrict__ hq_h16, const ushort* __restrict__ hk_h16,
    const float* __restrict__ sig_raw, const float* __restrict__ bvp,
    ushort* __restrict__ ctx) {
  __shared__ ushort sK[2][64*64];
  __shared__ ushort sV[2][64*64];
  __shared__ ushort sP[4*16*64];

  // XCD remap: 512 blocks, 4 bh per XCD, 16 q-tiles each
  const int id = blockIdx.x;
  const int loc = id >> 3;
  const int bh = (id & 7) * 4 + (loc >> 4);
  const int b = bh >> 4, h = bh & 15;
  const int t0 = (loc & 15) * 64;
  const int tid = threadIdx.x;
  const int wv = tid >> 6, lane = tid & 63;
  const int c = lane & 15, g = lane >> 4;
  const int qbase = t0 + wv * 16;
  const size_t rowstr = (size_t)B_ * E_;
  const size_t qoff = ((size_t)(qbase + c) * B_ + b) * E_ + h * 64;

  short8 qf[2];
  half8  hqf[2];
  #pragma unroll
  for (int cs = 0; cs < 2; ++cs) {
    qf[cs]  = *(const short8*)&q_bf[qoff + cs*32 + g*8];
    hqf[cs] = *(const half8*)&hq_h16[qoff + cs*32 + g*8];
  }

  // staging geometry: wave wv stages rows [wv*16, wv*16+16) of the tile
  const int str0 = wv*16 + (lane >> 3);
  const int str1 = str0 + 8;
  const int chk0 = ((lane & 7) ^ (str0 & 7)) * 8;
  const int chk1 = ((lane & 7) ^ (str1 & 7)) * 8;
  const int ldsst = (wv*16) * 64;

  // ------------------- pass 1: alignment softmax -> mean -------------------
  float den = 0.f, num = 0.f;
  {
    gld16(hk_h16 + ((size_t)str0 * B_ + b) * E_ + h*64 + chk0, &sK[0][ldsst]);
    gld16(hk_h16 + ((size_t)str1 * B_ + b) * E_ + h*64 + chk1, &sK[0][ldsst + 512]);
    __syncthreads();
    for (int t = 0; t < 16; ++t) {
      const ushort* kb = sK[t & 1];
      if (t < 15) {
        int s0n = (t+1) * 64;
        gld16(hk_h16 + ((size_t)(s0n + str0) * B_ + b) * E_ + h*64 + chk0,
              &sK[(t+1) & 1][ldsst]);
        gld16(hk_h16 + ((size_t)(s0n + str1) * B_ + b) * E_ + h*64 + chk1,
              &sK[(t+1) & 1][ldsst + 512]);
      }
      f32x4 acc[4] = {};
      __builtin_amdgcn_s_setprio(1);
      #pragma unroll
      for (int m = 0; m < 4; ++m)
        #pragma unroll
        for (int cs = 0; cs < 2; ++cs)
          acc[m] = __builtin_amdgcn_mfma_f32_16x16x32_f16(
              *(const half8*)&kb[SWZ(c + 16*m, cs*32 + g*8)], hqf[cs], acc[m], 0,0,0);
      __builtin_amdgcn_s_setprio(0);

      float fs = (float)(t*64 + 4*g);
      #pragma unroll
      for (int m = 0; m < 4; ++m)
        #pragma unroll
        for (int r = 0; r < 4; ++r) {
          float e = EXP2(acc[m][r]);
          den += e;
          num += e * (fs + (float)(16*m + r));
        }
      __syncthreads();
    }
  }
  den += __shfl_xor(den, 16); den += __shfl_xor(den, 32);
  num += __shfl_xor(num, 16); num += __shfl_xor(num, 32);
  const float meanq = num / den;              // q = qbase + c (uniform in g)
  const float graw = sig_raw[(size_t)(qbase + c) * B_ + b] + bvp[0];
  const float sgm = 1.f + 1.f/(1.f + __expf(-graw));
  const float fct = -LOG2E_ / (2.f * sgm * sgm);

  // ------------------- pass 2: content softmax + PV -------------------------
  f32x4 accO[4] = {};                         // O[q=4g+r][d=16n+c]
  float denq = 0.f;
  {
    gld16(k_bf + ((size_t)str0 * B_ + b) * E_ + h*64 + chk0, &sK[0][ldsst]);
    gld16(k_bf + ((size_t)str1 * B_ + b) * E_ + h*64 + chk1, &sK[0][ldsst + 512]);
    {
      int s2 = (tid & 31) * 2, d0 = (tid >> 5) * 8;
      size_t off0 = ((size_t)s2 * B_ + b) * E_ + h * 64 + d0;
      uint4 ra = *(const uint4*)&v_bf[off0];
      uint4 rb = *(const uint4*)&v_bf[off0 + rowstr];
      const ushort* pa = (const ushort*)&ra;
      const ushort* pb = (const ushort*)&rb;
      #pragma unroll
      for (int j = 0; j < 8; ++j)
        *(unsigned*)&sV[0][SWZ(d0 + j, s2)] = (unsigned)pa[j] | ((unsigned)pb[j] << 16);
    }
    __syncthreads();

    const int s2v = (tid & 31) * 2, d0v = (tid >> 5) * 8;
    for (int t = 0; t < 16; ++t) {
      const int cur = t & 1;
      const ushort* kb = sK[cur];
      const ushort* vb = sV[cur];
      uint4 ra, rb;
      if (t < 15) {
        int s0n = (t+1) * 64;
        gld16(k_bf + ((size_t)(s0n + str0) * B_ + b) * E_ + h*64 + chk0,
              &sK[cur^1][ldsst]);
        gld16(k_bf + ((size_t)(s0n + str1) * B_ + b) * E_ + h*64 + chk1,
              &sK[cur^1][ldsst + 512]);
        size_t off0 = ((size_t)(s0n + s2v) * B_ + b) * E_ + h * 64 + d0v;
        ra = *(const uint4*)&v_bf[off0];
        rb = *(const uint4*)&v_bf[off0 + rowstr];
      }

      f32x4 accL[4] = {};
      __builtin_amdgcn_s_setprio(1);
      #pragma unroll
      for (int m = 0; m < 4; ++m)
        #pragma unroll
        for (int cs = 0; cs < 2; ++cs)
          accL[m] = __builtin_amdgcn_mfma_f32_16x16x32_bf16(
              *(const short8*)&kb[SWZ(c + 16*m, cs*32 + g*8)], qf[cs], accL[m], 0,0,0);
      __builtin_amdgcn_s_setprio(0);

      float fs = (float)(t*64 + 4*g);
      float psum = 0.f;
      #pragma unroll
      for (int m = 0; m < 4; ++m) {
        float pr[4];
        #pragma unroll
        for (int r = 0; r < 4; ++r) {
          float dd = fs + (float)(16*m + r) - meanq;
          pr[r] = EXP2(accL[m][r] + fct * dd * dd);
          psum += pr[r];
        }
        uint2 uu;
        uu.x = cvtpk_bf16(pr[0], pr[1]);
        uu.y = cvtpk_bf16(pr[2], pr[3]);
        *(uint2*)&sP[wv*1024 + SWZ(c, 16*m + 4*g)] = uu;
      }
      denq += psum;

      __builtin_amdgcn_s_setprio(1);
      #pragma unroll
      for (int n = 0; n < 4; ++n)
        #pragma unroll
        for (int cs = 0; cs < 2; ++cs)
          accO[n] = __builtin_amdgcn_mfma_f32_16x16x32_bf16(
              *(const short8*)&sP[wv*1024 + SWZ(c, cs*32 + 8*g)],
              *(const short8*)&vb[SWZ(c + 16*n, cs*32 + 8*g)],
              accO[n], 0,0,0);
      __builtin_amdgcn_s_setprio(0);

      if (t < 15) {
        const ushort *pa = (const ushort*)&ra, *pb = (const ushort*)&rb;
        #pragma unroll
        for (int j = 0; j < 8; ++j)
          *(unsigned*)&sV[cur^1][SWZ(d0v + j, s2v)] = (unsigned)pa[j] | ((unsigned)pb[j] << 16);
      }
      __syncthreads();
    }
  }

  denq += __shfl_xor(denq, 16);
  denq += __shfl_xor(denq, 32);
  float dinv[4];
  #pragma unroll
  for (int r = 0; r < 4; ++r) dinv[r] = 1.f / __shfl(denq, 4*g + r);

  #pragma unroll
  for (int r = 0; r < 4; ++r) {
    size_t row = ((size_t)(qbase + 4*g + r) * B_ + b) * E_ + h * 64;
    #pragma unroll
    for (int n = 0; n < 4; ++n)
      ctx[row + 16*n + c] = f2bf(accO[n][r] * dinv[r]);
  }
}

// ---------------------------------------------------------------------------
extern "C" void kernel_launch(void* const* d_in, const int* in_sizes, int n_in,
                              void* d_out, int out_size, void* d_ws, size_t ws_size,
                              hipStream_t stream) {
  const float* query  = (const float*)d_in[0];
  const float* key_in = (const float*)d_in[1];
  const float* value  = (const float*)d_in[2];
  const float* Wq  = (const float*)d_in[3];  const float* bq  = (const float*)d_in[4];
  const float* Wk  = (const float*)d_in[5];  const float* bk  = (const float*)d_in[6];
  const float* Wv  = (const float*)d_in[7];  const float* bv  = (const float*)d_in[8];
  const float* Whq = (const float*)d_in[9];  const float* bhq = (const float*)d_in[10];
  const float* Whk = (const float*)d_in[11]; const float* bhk = (const float*)d_in[12];
  const float* Wwp = (const float*)d_in[13]; const float* bwp = (const float*)d_in[14];
  const float* Wvp = (const float*)d_in[15]; const float* bvp = (const float*)d_in[16];
  const float* Wo  = (const float*)d_in[17]; const float* bo  = (const float*)d_in[18];

  const size_t AU = (size_t)M_ * E_;       // 2M elems -> 4MB @16bit
  const size_t WU = (size_t)E_ * E_;       // 1M elems -> 2MB @16bit
  char* p = (char*)d_ws;
  float*  sig       = (float*)p;  p += 16384;   // raw sigma accumulator (2048 f32)
  ushort* query_bf  = (ushort*)p; p += AU*2;
  ushort* key_bf    = (ushort*)p; p += AU*2;
  ushort* value_bf  = (ushort*)p; p += AU*2;
  ushort* query_h16 = (ushort*)p; p += AU*2;   // -> ctx_bf after GEMMs
  ushort* key_h16   = (ushort*)p; p += AU*2;
  ushort* Whq_h16   = (ushort*)p; p += WU*2;
  ushort* Whk_h16   = (ushort*)p; p += WU*2;
  ushort* Wq_bf     = (ushort*)p; p += WU*2;
  ushort* Wk_bf     = (ushort*)p; p += WU*2;
  ushort* Wv_bf     = (ushort*)p; p += WU*2;
  ushort* Wwp_bf    = (ushort*)p; p += WU*2;
  ushort* Wo_bf     = (ushort*)p; p += WU*2;
  ushort* hq_h16    = (ushort*)p; p += AU*2;
  ushort* hk_h16    = (ushort*)p; p += AU*2;
  ushort* q_bf      = (ushort*)p; p += AU*2;
  ushort* k_bf      = (ushort*)p; p += AU*2;
  ushort* v_out     = (ushort*)p; p += AU*2;
  ushort* ctx_bf    = query_h16;               // dead after merged GEMMs

  // conv: all precision conversions in one launch; also zeroes sig
  {
    CvtArgs a{};
    a.d[0] = {query,  query_bf, query_h16, (int)(AU/4)};
    a.d[1] = {key_in, key_bf,   key_h16,   (int)(AU/4)};
    a.d[2] = {value,  value_bf, nullptr,   (int)(AU/4)};
    a.d[3] = {Whq,    nullptr,  Whq_h16,   (int)(WU/4)};
    a.d[4] = {Whk,    nullptr,  Whk_h16,   (int)(WU/4)};
    a.d[5] = {Wq,     Wq_bf,    nullptr,   (int)(WU/4)};
    a.d[6] = {Wk,     Wk_bf,    nullptr,   (int)(WU/4)};
    a.d[7] = {Wv,     Wv_bf,    nullptr,   (int)(WU/4)};
    a.d[8] = {Wwp,    Wwp_bf,   nullptr,   (int)(WU/4)};
    a.d[9] = {Wo,     Wo_bf,    nullptr,   (int)(WU/4)};
    a.zero = sig; a.zn = M_;
    cvt_kernel<<<dim3(128, 10), 256, 0, stream>>>(a);
  }
  // ALL 6 projection GEMMs in ONE launch (1536 blocks, XCD-remapped).
  // wp segment (flags=1) fuses the sigma dot into its epilogue -> sig.
  {
    GemmArgs a{};
    a.s[0] = {query_bf,  Wq_bf,   bq,  q_bf,   nullptr, nullptr, SCALE_*LOG2E_, 0};
    a.s[1] = {query_bf,  Wwp_bf,  bwp, nullptr, sig,    Wvp,     1.f,           1};
    a.s[2] = {key_bf,    Wk_bf,   bk,  k_bf,   nullptr, nullptr, 1.f,           0};
    a.s[3] = {value_bf,  Wv_bf,   bv,  v_out,  nullptr, nullptr, 1.f,           0};
    a.s[4] = {query_h16, Whq_h16, bhq, hq_h16, nullptr, nullptr, SCALE_*LOG2E_, 2};
    a.s[5] = {key_h16,   Whk_h16, bhk, hk_h16, nullptr, nullptr, 1.f,           2};
    gemm_mfma<128><<<dim3(1536), 256, 0, stream>>>(a);
  }
  attn_mfma<<<dim3(512), 256, 0, stream>>>(
      q_bf, k_bf, v_out, hq_h16, hk_h16, sig, bvp, ctx_bf);
  // P3: output projection (fp32 out), 64x64 tiles -> 512 blocks, XCD-remapped
  {
    GemmArgs a{};
    a.s[0] = {ctx_bf, Wo_bf, bo, nullptr, (float*)d_out, nullptr, 1.f, 0};
    gemm_mfma<64><<<dim3(512), 256, 0, stream>>>(a);
  }
}